// Round 11
// baseline (129.485 us; speedup 1.0000x reference)
//
#include <hip/hip_runtime.h>
#include <hip/hip_bf16.h>

// B=8, S=2048, H=512. out[b,i,:] = sum_{j<i} exp(q_i.x_j) x_j / (sum_{j<i} exp(q_i.x_j) + 1e-10)
// q = X @ W^T + b.
// R11: R7 structure (3 GEMMs, paired pvgemm, uniform sgemm) + DEPTH-3 gl_lds ring
//   (4 LDS buffers, issue stage k+3, counted vmcnt 8/4/0 resp. 6/3/0 - never 0 mid-loop)
//   to cover L3 (Infinity Cache) latency ~900cy that depth-2 could not.
//   Both-sides XOR swizzle (validated R10). wconv merged into prep.
#define BATCH 8
#define SEQ   2048
#define DIM   512

typedef __bf16 bf16x8 __attribute__((ext_vector_type(8)));
typedef float  f32x4  __attribute__((ext_vector_type(4)));

__device__ __forceinline__ ushort f2bf(float f) {
    union { float f; unsigned u; } c; c.f = f;
    unsigned u = c.u;
    u += 0x7fffu + ((u >> 16) & 1u);   // round-to-nearest-even
    return (ushort)(u >> 16);
}

// async global->LDS, 16B/lane; LDS dest wave-uniform base, global src per-lane
__device__ __forceinline__ void gl_lds(const ushort* g, ushort* l) {
    __builtin_amdgcn_global_load_lds(
        (const __attribute__((address_space(1))) void*)g,
        (__attribute__((address_space(3))) void*)l, 16, 0, 0);
}

#define VMW8 { asm volatile("s_waitcnt vmcnt(8)" ::: "memory"); __builtin_amdgcn_sched_barrier(0); }
#define VMW6 { asm volatile("s_waitcnt vmcnt(6)" ::: "memory"); __builtin_amdgcn_sched_barrier(0); }
#define VMW4 { asm volatile("s_waitcnt vmcnt(4)" ::: "memory"); __builtin_amdgcn_sched_barrier(0); }
#define VMW3 { asm volatile("s_waitcnt vmcnt(3)" ::: "memory"); __builtin_amdgcn_sched_barrier(0); }
#define VMW0 { asm volatile("s_waitcnt vmcnt(0)" ::: "memory"); __builtin_amdgcn_sched_barrier(0); }
#define SBAR { __builtin_amdgcn_s_barrier(); __builtin_amdgcn_sched_barrier(0); }

// ---------------- prep: X f32 -> Xb bf16 + Xt bf16 (transposed); tail blocks do W->bf16 -------
__global__ __launch_bounds__(256) void prep_kernel(const float* __restrict__ X,
                                                   ushort* __restrict__ Xb,
                                                   ushort* __restrict__ Xt,
                                                   const float* __restrict__ W,
                                                   ushort* __restrict__ Wb) {
    __shared__ ushort T[32 * 33];
    int t   = threadIdx.x;
    int bid = blockIdx.x;              // 8192 X-blocks + 128 W-blocks
    if (bid >= 8192) {
        int gt = (bid - 8192) * 256 + t;
        size_t base = (size_t)gt * 8;
        float4 a = *(const float4*)(W + base);
        float4 c = *(const float4*)(W + base + 4);
        ushort4 lo, hi;
        lo.x = f2bf(a.x); lo.y = f2bf(a.y); lo.z = f2bf(a.z); lo.w = f2bf(a.w);
        hi.x = f2bf(c.x); hi.y = f2bf(c.y); hi.z = f2bf(c.z); hi.w = f2bf(c.w);
        *(ushort4*)(Wb + base)     = lo;
        *(ushort4*)(Wb + base + 4) = hi;
        return;
    }
    int b   = bid >> 10;
    int st  = (bid >> 4) & 63;
    int ht  = bid & 15;
    int s0 = st * 32, h0 = ht * 32;

    int r  = t >> 3;
    int c4 = (t & 7) * 4;
    size_t src = ((size_t)(b * SEQ + s0 + r)) * DIM + h0 + c4;
    float4 v = *(const float4*)(X + src);
    ushort u0 = f2bf(v.x), u1 = f2bf(v.y), u2 = f2bf(v.z), u3 = f2bf(v.w);
    ushort4 uv; uv.x = u0; uv.y = u1; uv.z = u2; uv.w = u3;
    *(ushort4*)(Xb + src) = uv;
    T[(c4 + 0) * 33 + r] = u0;
    T[(c4 + 1) * 33 + r] = u1;
    T[(c4 + 2) * 33 + r] = u2;
    T[(c4 + 3) * 33 + r] = u3;
    __syncthreads();
    int hh = t >> 3;
    int sc = (t & 7) * 4;
    ushort4 w;
    w.x = T[hh * 33 + sc + 0];
    w.y = T[hh * 33 + sc + 1];
    w.z = T[hh * 33 + sc + 2];
    w.w = T[hh * 33 + sc + 3];
    *(ushort4*)(Xt + ((size_t)(b * DIM + h0 + hh)) * SEQ + s0 + sc) = w;
}

// Swizzled fragment reads from ring buffer R: short idx = row*32 + ((lg*8) ^ ((ln&3)<<3))
#define GEMM_COMPUTE(R)                                                                    \
    {                                                                                      \
        bf16x8 af[4], bfr[4];                                                              \
        _Pragma("unroll") for (int r = 0; r < 4; ++r)                                      \
            af[r] = *(const bf16x8*)&Ab[R][(wr * 64 + r * 16 + ln) * 32 + rxor];           \
        _Pragma("unroll") for (int cc = 0; cc < 4; ++cc)                                   \
            bfr[cc] = *(const bf16x8*)&Bb[R][(wc * 64 + cc * 16 + ln) * 32 + rxor];        \
        _Pragma("unroll") for (int r = 0; r < 4; ++r)                                      \
            _Pragma("unroll") for (int cc = 0; cc < 4; ++cc)                               \
                acc[r][cc] = __builtin_amdgcn_mfma_f32_16x16x32_bf16(af[r], bfr[cc],       \
                                                                     acc[r][cc], 0, 0, 0); \
    }

// Depth-3 ring loop (4 buffers). STAGE = 4 gl_lds/wave -> waits 8/4/0.
#define RING4_LOOP(N, STAGE)                                    \
    STAGE(0, 0)                                                 \
    STAGE(1, 1)                                                 \
    STAGE(2, 2)                                                 \
    for (int k = 0; k < (N); ++k) {                             \
        if (k < (N) - 2) { VMW8 } else if (k == (N) - 2) { VMW4 } else { VMW0 } \
        SBAR                                                    \
        if (k + 3 < (N)) { int rr = (k + 3) & 3; STAGE(k + 3, rr) } \
        GEMM_COMPUTE((k & 3))                                   \
    }

// ---------------- qgemm: Qb = bf16(Xb @ Wb^T + bias) ----------------
__global__ __launch_bounds__(256, 2) void qgemm_kernel(const ushort* __restrict__ Xb,
                                                       const ushort* __restrict__ Wb,
                                                       const float* __restrict__ bias,
                                                       ushort* __restrict__ Qb) {
    __shared__ ushort Ab[4][128 * 32];
    __shared__ ushort Bb[4][128 * 32];
    int t   = threadIdx.x;
    int bid = blockIdx.x;              // 128 mtiles * 4 ntiles
    int mt = bid >> 2, nt = bid & 3;
    int m0 = mt << 7, n0 = nt << 7;
    int w  = t >> 6, l = t & 63, ln = l & 15, lg = l >> 4;
    int wr = w >> 1, wc = w & 1;
    int sr   = l >> 2;
    int swo  = ((l & 3) * 8) ^ ((sr & 3) << 3);
    int rxor = (lg * 8) ^ ((ln & 3) << 3);
    int r0s  = w * 32;

    f32x4 acc[4][4] = {};
    const ushort* Arow = Xb + (size_t)m0 * 512;
    const ushort* Brow = Wb + (size_t)n0 * 512;

#define QG_STAGE(S, R)                                                                          \
    {                                                                                           \
        gl_lds(Arow + (size_t)(r0s + sr) * 512 + (S) * 32 + swo,      &Ab[R][r0s * 32]);        \
        gl_lds(Arow + (size_t)(r0s + 16 + sr) * 512 + (S) * 32 + swo, &Ab[R][(r0s + 16) * 32]); \
        gl_lds(Brow + (size_t)(r0s + sr) * 512 + (S) * 32 + swo,      &Bb[R][r0s * 32]);        \
        gl_lds(Brow + (size_t)(r0s + 16 + sr) * 512 + (S) * 32 + swo, &Bb[R][(r0s + 16) * 32]); \
    }

    RING4_LOOP(16, QG_STAGE)

    float bv[4];
#pragma unroll
    for (int c = 0; c < 4; ++c) bv[c] = bias[n0 + wc * 64 + c * 16 + ln];
#pragma unroll
    for (int r = 0; r < 4; ++r)
#pragma unroll
        for (int c = 0; c < 4; ++c)
#pragma unroll
            for (int q = 0; q < 4; ++q) {
                int row = m0 + wr * 64 + r * 16 + lg * 4 + q;
                int col = n0 + wc * 64 + c * 16 + ln;
                Qb[(size_t)row * 512 + col] = f2bf(acc[r][c][q] + bv[c]);
            }
}

// ---------------- sgemm: P = exp(mask(Q X^T)) packed lower-tri tiles + rowsum->den ------------
__global__ __launch_bounds__(256, 2) void sgemm_kernel(const ushort* __restrict__ Qb,
                                                       const ushort* __restrict__ Xb,
                                                       ushort* __restrict__ Pb,
                                                       float* __restrict__ den,
                                                       int g0, int G) {
    __shared__ ushort Ab[4][128 * 32];
    __shared__ ushort Bb[4][128 * 32];
    int t  = threadIdx.x;
    int bL = blockIdx.x;
    int b  = g0 + bL;
    int c  = blockIdx.y;               // 0..135, grouped by it (shares Qb panel)
    int it = 0, base = 0;
    for (;;) { if (c < base + it + 1) break; base += it + 1; ++it; }
    int jt = c - base;

    int m0 = it << 7, n0 = jt << 7;
    int w  = t >> 6, l = t & 63, ln = l & 15, lg = l >> 4;
    int wr = w >> 1, wc = w & 1;
    int sr   = l >> 2;
    int swo  = ((l & 3) * 8) ^ ((sr & 3) << 3);
    int rxor = (lg * 8) ^ ((ln & 3) << 3);
    int r0s  = w * 32;

    const ushort* Arow = Qb + (size_t)(b * SEQ + m0) * 512;
    const ushort* Brow = Xb + (size_t)(b * SEQ + n0) * 512;
    f32x4 acc[4][4] = {};

#define SG_STAGE(S, R)                                                                          \
    {                                                                                           \
        gl_lds(Arow + (size_t)(r0s + sr) * 512 + (S) * 32 + swo,      &Ab[R][r0s * 32]);        \
        gl_lds(Arow + (size_t)(r0s + 16 + sr) * 512 + (S) * 32 + swo, &Ab[R][(r0s + 16) * 32]); \
        gl_lds(Brow + (size_t)(r0s + sr) * 512 + (S) * 32 + swo,      &Bb[R][r0s * 32]);        \
        gl_lds(Brow + (size_t)(r0s + 16 + sr) * 512 + (S) * 32 + swo, &Bb[R][(r0s + 16) * 32]); \
    }

    RING4_LOOP(16, SG_STAGE)

    ushort* ptile = Pb + ((size_t)c * G + bL) * 16384;
#pragma unroll
    for (int r = 0; r < 4; ++r)
#pragma unroll
        for (int q = 0; q < 4; ++q) {
            int row  = wr * 64 + r * 16 + lg * 4 + q;       // local i
            int grow = m0 + row;                            // in-batch i
            float rs = 0.f;
#pragma unroll
            for (int cc = 0; cc < 4; ++cc) {
                int col = n0 + wc * 64 + cc * 16 + ln;      // in-batch j
                float ex = (col < grow) ? __expf(acc[r][cc][q]) : 0.f;
                rs += ex;
                ptile[row * 128 + (wc * 64 + cc * 16 + ln)] = f2bf(ex);
            }
            rs += __shfl_xor(rs, 1);
            rs += __shfl_xor(rs, 2);
            rs += __shfl_xor(rs, 4);
            rs += __shfl_xor(rs, 8);
            if (ln == 0) unsafeAtomicAdd(&den[b * SEQ + grow], rs);
        }
}

// ---------------- pvgemm: out = (P @ X) * 1/(den+1e-10), paired it-tiles, depth-3 ring --------
// blockIdx.y in [0,64): p = y>>3 -> halves it=15-p then it=p (uniform 68 K-steps);
// ht = y&7 -> 64-col slice. Full-K ownership, plain stores. 3 gl_lds/stage -> waits 6/3/0.
__global__ __launch_bounds__(256, 2) void pvgemm_kernel(const ushort* __restrict__ Pb,
                                                        const ushort* __restrict__ Xt,
                                                        const float* __restrict__ den,
                                                        float* __restrict__ out,
                                                        int g0, int G) {
    __shared__ ushort Ab[4][128 * 32];
    __shared__ ushort Bb[4][64 * 32];
    int t  = threadIdx.x;
    int bL = blockIdx.x;
    int b  = g0 + bL;
    int y  = blockIdx.y;
    int p  = y >> 3;                   // 0..7
    int ht = y & 7;                    // 0..7
    int n0 = ht << 6;

    int w = t >> 6, l = t & 63, ln = l & 15, lg = l >> 4;
    int wr = w >> 1, wc = w & 1;       // wave tile: rows wr*64.., cols wc*32..
    int sr   = l >> 2;
    int swo  = ((l & 3) * 8) ^ ((sr & 3) << 3);
    int rxor = (lg * 8) ^ ((ln & 3) << 3);
    int r0s  = w * 32;

    const ushort* BrowX = Xt + ((size_t)b * DIM + n0) * SEQ;

#define PV_STAGE(S, R)                                                                      \
    {                                                                                       \
        const ushort* pt = Pb + ((size_t)(Tit + ((S) >> 2)) * G + bL) * 16384               \
                           + ((S) & 3) * 32;                                                \
        gl_lds(pt + (size_t)(r0s + sr) * 128 + swo,      &Ab[R][r0s * 32]);                 \
        gl_lds(pt + (size_t)(r0s + 16 + sr) * 128 + swo, &Ab[R][(r0s + 16) * 32]);          \
        gl_lds(BrowX + (size_t)(w * 16 + sr) * 2048 + (S) * 32 + swo, &Bb[R][(w * 16) * 32]); \
    }

    for (int half = 0; half < 2; ++half) {
        int it  = half ? p : (15 - p);
        int Tit = (it * (it + 1)) >> 1;
        int N   = (it + 1) * 4;
        int m0  = it << 7;
        f32x4 acc[4][2] = {};

        PV_STAGE(0, 0)
        PV_STAGE(1, 1)
        PV_STAGE(2, 2)
        for (int k = 0; k < N; ++k) {
            if (k < N - 2) { VMW6 } else if (k == N - 2) { VMW3 } else { VMW0 }
            SBAR
            if (k + 3 < N) { int rr = (k + 3) & 3; PV_STAGE(k + 3, rr) }
            {
                int R = k & 3;
                bf16x8 af[4], bfr[2];
#pragma unroll
                for (int r = 0; r < 4; ++r)
                    af[r] = *(const bf16x8*)&Ab[R][(wr * 64 + r * 16 + ln) * 32 + rxor];
#pragma unroll
                for (int cc = 0; cc < 2; ++cc)
                    bfr[cc] = *(const bf16x8*)&Bb[R][(wc * 32 + cc * 16 + ln) * 32 + rxor];
#pragma unroll
                for (int r = 0; r < 4; ++r)
#pragma unroll
                    for (int cc = 0; cc < 2; ++cc)
                        acc[r][cc] = __builtin_amdgcn_mfma_f32_16x16x32_bf16(af[r], bfr[cc],
                                                                             acc[r][cc], 0, 0, 0);
            }
        }

#pragma unroll
        for (int r = 0; r < 4; ++r)
#pragma unroll
            for (int q = 0; q < 4; ++q) {
                int row = m0 + wr * 64 + r * 16 + lg * 4 + q;
                float inv = 1.0f / (den[b * SEQ + row] + 1e-10f);
                size_t o = (size_t)(b * SEQ + row) * 512;
#pragma unroll
                for (int cc = 0; cc < 2; ++cc)
                    out[o + n0 + wc * 32 + cc * 16 + ln] = acc[r][cc][q] * inv;
            }
        __syncthreads();               // drain + protect ring buffers before next half
    }
}

extern "C" void kernel_launch(void* const* d_in, const int* in_sizes, int n_in,
                              void* d_out, int out_size, void* d_ws, size_t ws_size,
                              hipStream_t stream) {
    const float* X    = (const float*)d_in[0];
    const float* W    = (const float*)d_in[1];
    const float* bias = (const float*)d_in[2];
    float* out = (float*)d_out;

    // ws layout (bytes): Xb[16.78M] | Xt[16.78M] | Qb[16.78M] | Wb[0.52M] | den[64K] | Pb[G*4.46M]
    ushort* ws = (ushort*)d_ws;
    ushort* Xb = ws;
    ushort* Xt = ws + 8388608;
    ushort* Qb = ws + 16777216;
    ushort* Wb = ws + 25165824;
    float*  den = (float*)((char*)d_ws + 50855936);
    ushort* Pb = (ushort*)((char*)d_ws + 50921472);

    size_t avail = (ws_size > 50921472) ? (ws_size - 50921472) : 0;
    int G = 1;
    while (G < 8 && (size_t)(G * 2) * 4456448 <= avail) G *= 2;

    hipMemsetAsync(den, 0, (size_t)BATCH * SEQ * sizeof(float), stream);
    prep_kernel<<<dim3(8320), dim3(256), 0, stream>>>(X, Xb, Xt, W, Wb);
    qgemm_kernel<<<dim3(512), dim3(256), 0, stream>>>(Xb, Wb, bias, Qb);
    for (int g0 = 0; g0 < BATCH; g0 += G) {
        sgemm_kernel<<<dim3(G, 136), dim3(256), 0, stream>>>(Qb, Xb, Pb, den, g0, G);
        pvgemm_kernel<<<dim3(G, 64), dim3(256), 0, stream>>>(Pb, Xt, den, out, g0, G);
    }
}

// Round 12
// 127.257 us; speedup vs baseline: 1.0175x; 1.0175x over previous
//
#include <hip/hip_runtime.h>
#include <hip/hip_bf16.h>

// B=8, S=2048, H=512. out[b,i,:] = sum_{j<i} exp(q_i.x_j) x_j / (sum_{j<i} exp(q_i.x_j) + 1e-10)
// q = X @ W^T + b.
// R12: sgemm/qgemm -> 256x128 tiles, 8 waves (512 thr), depth-2 reg staging (R7 discipline),
//      pitch-40 LDS, 60KB -> 2 blocks/CU (16 waves/CU). pvgemm kept exactly R7 as control.
//      sgemm writes the same packed-128^2 P-tile format (two it-halves per block; off-tri
//      half-tile (2rt, 2rt+1) skipped - fully masked anyway).
#define BATCH 8
#define SEQ   2048
#define DIM   512

typedef __bf16 bf16x8 __attribute__((ext_vector_type(8)));
typedef float  f32x4  __attribute__((ext_vector_type(4)));

__device__ __forceinline__ ushort f2bf(float f) {
    union { float f; unsigned u; } c; c.f = f;
    unsigned u = c.u;
    u += 0x7fffu + ((u >> 16) & 1u);   // round-to-nearest-even
    return (ushort)(u >> 16);
}

// ---------------- prep: X f32 -> Xb bf16 + Xt bf16 (transposed); tail blocks do W->bf16 -------
__global__ __launch_bounds__(256) void prep_kernel(const float* __restrict__ X,
                                                   ushort* __restrict__ Xb,
                                                   ushort* __restrict__ Xt,
                                                   const float* __restrict__ W,
                                                   ushort* __restrict__ Wb) {
    __shared__ ushort T[32 * 33];
    int t   = threadIdx.x;
    int bid = blockIdx.x;              // 8192 X-blocks + 128 W-blocks
    if (bid >= 8192) {
        int gt = (bid - 8192) * 256 + t;
        size_t base = (size_t)gt * 8;
        float4 a = *(const float4*)(W + base);
        float4 c = *(const float4*)(W + base + 4);
        ushort4 lo, hi;
        lo.x = f2bf(a.x); lo.y = f2bf(a.y); lo.z = f2bf(a.z); lo.w = f2bf(a.w);
        hi.x = f2bf(c.x); hi.y = f2bf(c.y); hi.z = f2bf(c.z); hi.w = f2bf(c.w);
        *(ushort4*)(Wb + base)     = lo;
        *(ushort4*)(Wb + base + 4) = hi;
        return;
    }
    int b   = bid >> 10;
    int st  = (bid >> 4) & 63;
    int ht  = bid & 15;
    int s0 = st * 32, h0 = ht * 32;

    int r  = t >> 3;
    int c4 = (t & 7) * 4;
    size_t src = ((size_t)(b * SEQ + s0 + r)) * DIM + h0 + c4;
    float4 v = *(const float4*)(X + src);
    ushort u0 = f2bf(v.x), u1 = f2bf(v.y), u2 = f2bf(v.z), u3 = f2bf(v.w);
    ushort4 uv; uv.x = u0; uv.y = u1; uv.z = u2; uv.w = u3;
    *(ushort4*)(Xb + src) = uv;
    T[(c4 + 0) * 33 + r] = u0;
    T[(c4 + 1) * 33 + r] = u1;
    T[(c4 + 2) * 33 + r] = u2;
    T[(c4 + 3) * 33 + r] = u3;
    __syncthreads();
    int hh = t >> 3;
    int sc = (t & 7) * 4;
    ushort4 w;
    w.x = T[hh * 33 + sc + 0];
    w.y = T[hh * 33 + sc + 1];
    w.z = T[hh * 33 + sc + 2];
    w.w = T[hh * 33 + sc + 3];
    *(ushort4*)(Xt + ((size_t)(b * DIM + h0 + hh)) * SEQ + s0 + sc) = w;
}

// ============ 256x128-tile GEMM pieces: 8 waves (4 row x 2 col of 64x64), pitch-40 LDS ========
// staging A (256x32): thread t: row=t>>1 (0..255), colbase=(t&1)*16 -> two uint4
// staging B (128x32): thread t: row=t>>2 (0..127), col=(t&3)*8    -> one uint4
#define C256_COMPUTE(CUR)                                                                  \
    {                                                                                      \
        bf16x8 af[4], bfr[4];                                                              \
        _Pragma("unroll") for (int r = 0; r < 4; ++r)                                      \
            af[r] = *(const bf16x8*)&At[CUR][(wrow * 64 + r * 16 + ln) * 40 + lg * 8];     \
        _Pragma("unroll") for (int cc = 0; cc < 4; ++cc)                                   \
            bfr[cc] = *(const bf16x8*)&Bt[CUR][(wcol * 64 + cc * 16 + ln) * 40 + lg * 8];  \
        _Pragma("unroll") for (int r = 0; r < 4; ++r)                                      \
            _Pragma("unroll") for (int cc = 0; cc < 4; ++cc)                               \
                acc[r][cc] = __builtin_amdgcn_mfma_f32_16x16x32_bf16(af[r], bfr[cc],       \
                                                                     acc[r][cc], 0, 0, 0); \
    }

#define C256_LOAD(KS)                                                                  \
    {                                                                                  \
        const ushort* pa_ = Arow + (size_t)arow * 512 + (KS) * 32 + acol;              \
        a0 = *(const uint4*)pa_;                                                       \
        a1 = *(const uint4*)(pa_ + 8);                                                 \
        b0 = *(const uint4*)(Brow + (size_t)brow * 512 + (KS) * 32 + bcol);            \
    }
#define C256_STORE(CUR)                                                                \
    {                                                                                  \
        *(uint4*)&At[CUR][arow * 40 + acol]     = a0;                                  \
        *(uint4*)&At[CUR][arow * 40 + acol + 8] = a1;                                  \
        *(uint4*)&Bt[CUR][brow * 40 + bcol]     = b0;                                  \
    }

// ---------------- qgemm: Qb = bf16(Xb @ Wb^T + bias), 256x128 tile ----------------
__global__ __launch_bounds__(512, 4) void qgemm_kernel(const ushort* __restrict__ Xb,
                                                       const ushort* __restrict__ Wb,
                                                       const float* __restrict__ bias,
                                                       ushort* __restrict__ Qb) {
    __shared__ ushort At[2][256 * 40];
    __shared__ ushort Bt[2][128 * 40];
    int t   = threadIdx.x;
    int bid = blockIdx.x;              // 64 mtiles * 4 ntiles
    int mt = bid >> 2, nt = bid & 3;
    int m0 = mt << 8, n0 = nt << 7;
    int w  = t >> 6, l = t & 63, ln = l & 15, lg = l >> 4;
    int wrow = w >> 1, wcol = w & 1;

    f32x4 acc[4][4] = {};
    const ushort* Arow = Xb + (size_t)m0 * 512;
    const ushort* Brow = Wb + (size_t)n0 * 512;
    int arow = t >> 1, acol = (t & 1) * 16;
    int brow = t >> 2, bcol = (t & 3) * 8;

    uint4 a0, a1, b0;
    C256_LOAD(0)
    C256_STORE(0)
    __syncthreads();
    int cur = 0;
    for (int ks = 0; ks < 16; ++ks) {
        if (ks < 15) C256_LOAD(ks + 1)
        C256_COMPUTE(cur)
        if (ks < 15) C256_STORE(cur ^ 1)
        __syncthreads();
        cur ^= 1;
    }

    float bv[4];
#pragma unroll
    for (int c = 0; c < 4; ++c) bv[c] = bias[n0 + wcol * 64 + c * 16 + ln];
#pragma unroll
    for (int r = 0; r < 4; ++r)
#pragma unroll
        for (int c = 0; c < 4; ++c)
#pragma unroll
            for (int q = 0; q < 4; ++q) {
                int row = m0 + wrow * 64 + r * 16 + lg * 4 + q;
                int col = n0 + wcol * 64 + c * 16 + ln;
                Qb[(size_t)row * 512 + col] = f2bf(acc[r][c][q] + bv[c]);
            }
}

// ---------------- sgemm: P = exp(mask(Q X^T)) -> packed 128^2 lower-tri tiles + den -----------
// 256x128 block = (rt, jt): rows rt*256..+255, cols jt*128..+127; jt in [0, 2rt+1].
// Writes P tiles (2rt, jt) [upper half, only jt<=2rt] and (2rt+1, jt) [lower half].
// Grid (72, 8): x = tile (heavy rt first), y = batch.
__global__ __launch_bounds__(512, 4) void sgemm_kernel(const ushort* __restrict__ Qb,
                                                       const ushort* __restrict__ Xb,
                                                       ushort* __restrict__ Pb,
                                                       float* __restrict__ den,
                                                       int g0, int G) {
    __shared__ ushort At[2][256 * 40];
    __shared__ ushort Bt[2][128 * 40];
    int t  = threadIdx.x;
    int bL = blockIdx.y;
    int b  = g0 + bL;
    int c  = blockIdx.x;               // 0..71, heavy rt first
    int rt = 7, rem = c;
    for (;;) { int n = 2 * rt + 2; if (rem < n) break; rem -= n; --rt; }
    int jt = rem;

    int m0 = rt << 8, n0 = jt << 7;
    int w  = t >> 6, l = t & 63, ln = l & 15, lg = l >> 4;
    int wrow = w >> 1, wcol = w & 1;

    const ushort* Arow = Qb + (size_t)(b * SEQ + m0) * 512;
    const ushort* Brow = Xb + (size_t)(b * SEQ + n0) * 512;

    f32x4 acc[4][4] = {};
    int arow = t >> 1, acol = (t & 1) * 16;
    int brow = t >> 2, bcol = (t & 3) * 8;

    uint4 a0, a1, b0;
    C256_LOAD(0)
    C256_STORE(0)
    __syncthreads();
    int cur = 0;
    for (int ks = 0; ks < 16; ++ks) {
        if (ks < 15) C256_LOAD(ks + 1)
        C256_COMPUTE(cur)
        if (ks < 15) C256_STORE(cur ^ 1)
        __syncthreads();
        cur ^= 1;
    }

    // epilogue: mask+exp, rowsum->den, store into packed 128^2 tile format
    int it   = 2 * rt + (wrow >> 1);               // which 128-row P tile
    bool ok  = (wrow >= 2) || (jt <= 2 * rt);      // skip off-triangle half-tile
    int Tidx = ((it * (it + 1)) >> 1) + jt;
    ushort* ptile = Pb + ((size_t)Tidx * G + bL) * 16384;
#pragma unroll
    for (int r = 0; r < 4; ++r)
#pragma unroll
        for (int q = 0; q < 4; ++q) {
            int lrow = wrow * 64 + r * 16 + lg * 4 + q;    // 0..255 local
            int grow = m0 + lrow;                          // in-batch i
            float rs = 0.f;
            float ex[4];
#pragma unroll
            for (int cc = 0; cc < 4; ++cc) {
                int col = n0 + wcol * 64 + cc * 16 + ln;   // in-batch j
                ex[cc] = (col < grow) ? __expf(acc[r][cc][q]) : 0.f;
                rs += ex[cc];
            }
            if (ok) {
                int prow = lrow & 127;
#pragma unroll
                for (int cc = 0; cc < 4; ++cc)
                    ptile[prow * 128 + (wcol * 64 + cc * 16 + ln)] = f2bf(ex[cc]);
            }
            rs += __shfl_xor(rs, 1);
            rs += __shfl_xor(rs, 2);
            rs += __shfl_xor(rs, 4);
            rs += __shfl_xor(rs, 8);
            if (ok && ln == 0) unsafeAtomicAdd(&den[b * SEQ + grow], rs);
        }
}

// ---------------- pvgemm: out = (P @ X) * 1/(den+1e-10), paired tiles, depth-2 (R7) -----------
__global__ __launch_bounds__(256, 2) void pvgemm_kernel(const ushort* __restrict__ Pb,
                                                        const ushort* __restrict__ Xt,
                                                        const float* __restrict__ den,
                                                        float* __restrict__ out,
                                                        int g0, int G) {
    __shared__ ushort Ap[2][128 * 40];
    __shared__ ushort Bp[2][64 * 40];
    int t  = threadIdx.x;
    int bL = blockIdx.x;
    int b  = g0 + bL;
    int y  = blockIdx.y;
    int p  = y >> 3;                   // 0..7
    int ht = y & 7;                    // 0..7
    int n0 = ht << 6;

    int w = t >> 6, l = t & 63, ln = l & 15, lg = l >> 4;
    int wr = w >> 1, wc = w & 1;       // wave tile: rows wr*64.., cols wc*32..
    int srow = t >> 2;                 // 0..63
    int sc8  = (t & 3) * 8;

    const ushort* BrowX = Xt + ((size_t)b * DIM + n0) * SEQ;

#define PV_LOAD(KK, A0, A1, B0)                                                    \
    {                                                                              \
        const ushort* ptile = Pb + ((size_t)(Tit + ((KK) >> 2)) * G + bL) * 16384  \
                              + ((KK) & 3) * 32;                                   \
        A0 = *(const uint4*)(ptile + srow * 128 + sc8);                            \
        A1 = *(const uint4*)(ptile + (64 + srow) * 128 + sc8);                     \
        B0 = *(const uint4*)(BrowX + (size_t)srow * SEQ + (KK) * 32 + sc8);        \
    }
#define PV_ST(CUR, A0, A1, B0)                              \
    {                                                       \
        *(uint4*)&Ap[CUR][srow * 40 + sc8]        = A0;     \
        *(uint4*)&Ap[CUR][(64 + srow) * 40 + sc8] = A1;     \
        *(uint4*)&Bp[CUR][srow * 40 + sc8]        = B0;     \
    }
#define PV_COMPUTE(CUR)                                                                   \
    {                                                                                     \
        bf16x8 af[4], bfr[2];                                                             \
        _Pragma("unroll") for (int r = 0; r < 4; ++r)                                     \
            af[r] = *(const bf16x8*)&Ap[CUR][(wr * 64 + r * 16 + ln) * 40 + lg * 8];      \
        _Pragma("unroll") for (int cc = 0; cc < 2; ++cc)                                  \
            bfr[cc] = *(const bf16x8*)&Bp[CUR][(wc * 32 + cc * 16 + ln) * 40 + lg * 8];   \
        _Pragma("unroll") for (int r = 0; r < 4; ++r)                                     \
            _Pragma("unroll") for (int cc = 0; cc < 2; ++cc)                              \
                acc[r][cc] = __builtin_amdgcn_mfma_f32_16x16x32_bf16(af[r], bfr[cc],      \
                                                                     acc[r][cc], 0, 0, 0);\
    }

    for (int half = 0; half < 2; ++half) {
        int it  = half ? p : (15 - p);
        int Tit = (it * (it + 1)) >> 1;
        int n   = (it + 1) * 4;
        int m0  = it << 7;
        f32x4 acc[4][2] = {};

        uint4 pA0, pA1, pB0, qA0, qA1, qB0;
        PV_LOAD(0, pA0, pA1, pB0)
        PV_LOAD(1, qA0, qA1, qB0)
        __syncthreads();               // prev half's readers done (no-op for half 0)
        PV_ST(0, pA0, pA1, pB0)
        __syncthreads();
        for (int ks = 0; ks < n - 2; ks += 2) {
            PV_LOAD(ks + 2, pA0, pA1, pB0)
            PV_COMPUTE(0)
            PV_ST(1, qA0, qA1, qB0)
            __syncthreads();
            if (ks + 3 < n) PV_LOAD(ks + 3, qA0, qA1, qB0)
            PV_COMPUTE(1)
            PV_ST(0, pA0, pA1, pB0)
            __syncthreads();
        }
        PV_COMPUTE(0)
        PV_ST(1, qA0, qA1, qB0)
        __syncthreads();
        PV_COMPUTE(1)

#pragma unroll
        for (int r = 0; r < 4; ++r)
#pragma unroll
            for (int q = 0; q < 4; ++q) {
                int row = m0 + wr * 64 + r * 16 + lg * 4 + q;
                float inv = 1.0f / (den[b * SEQ + row] + 1e-10f);
                size_t o = (size_t)(b * SEQ + row) * 512;
#pragma unroll
                for (int cc = 0; cc < 2; ++cc)
                    out[o + n0 + wc * 32 + cc * 16 + ln] = acc[r][cc][q] * inv;
            }
        __syncthreads();               // protect LDS before next half
    }
}

extern "C" void kernel_launch(void* const* d_in, const int* in_sizes, int n_in,
                              void* d_out, int out_size, void* d_ws, size_t ws_size,
                              hipStream_t stream) {
    const float* X    = (const float*)d_in[0];
    const float* W    = (const float*)d_in[1];
    const float* bias = (const float*)d_in[2];
    float* out = (float*)d_out;

    // ws layout (bytes): Xb[16.78M] | Xt[16.78M] | Qb[16.78M] | Wb[0.52M] | den[64K] | Pb[G*4.46M]
    ushort* ws = (ushort*)d_ws;
    ushort* Xb = ws;
    ushort* Xt = ws + 8388608;
    ushort* Qb = ws + 16777216;
    ushort* Wb = ws + 25165824;
    float*  den = (float*)((char*)d_ws + 50855936);
    ushort* Pb = (ushort*)((char*)d_ws + 50921472);

    size_t avail = (ws_size > 50921472) ? (ws_size - 50921472) : 0;
    int G = 1;
    while (G < 8 && (size_t)(G * 2) * 4456448 <= avail) G *= 2;

    hipMemsetAsync(den, 0, (size_t)BATCH * SEQ * sizeof(float), stream);
    prep_kernel<<<dim3(8320), dim3(256), 0, stream>>>(X, Xb, Xt, W, Wb);
    qgemm_kernel<<<dim3(256), dim3(512), 0, stream>>>(Xb, Wb, bias, Qb);
    for (int g0 = 0; g0 < BATCH; g0 += G) {
        sgemm_kernel<<<dim3(72, G), dim3(512), 0, stream>>>(Qb, Xb, Pb, den, g0, G);
        pvgemm_kernel<<<dim3(G, 64), dim3(256), 0, stream>>>(Pb, Xt, den, out, g0, G);
    }
}

// Round 13
// 117.976 us; speedup vs baseline: 1.0976x; 1.0787x over previous
//
#include <hip/hip_runtime.h>
#include <hip/hip_bf16.h>

// B=8, S=2048, H=512. out[b,i,:] = sum_{j<i} exp(q_i.x_j) x_j / (sum_{j<i} exp(q_i.x_j) + 1e-10)
// q = X @ W^T + b.
// R13: revert to R7 (best: 109.9us) + three local wins:
//   1) pvgemm computes den INLINE from its A-fragments (reads every P[i,:] once anyway)
//      -> sgemm loses shfl+atomic den epilogue; den buffer + memset deleted.
//   2) sgemm stores P-tile via LDS bounce -> 8 coalesced 16B stores/lane (was 16x 2B scattered).
//   3) residency: qgemm/sgemm (256,3), pvgemm (256,4).
#define BATCH 8
#define SEQ   2048
#define DIM   512

typedef __bf16 bf16x8 __attribute__((ext_vector_type(8)));
typedef float  f32x4  __attribute__((ext_vector_type(4)));

__device__ __forceinline__ ushort f2bf(float f) {
    union { float f; unsigned u; } c; c.f = f;
    unsigned u = c.u;
    u += 0x7fffu + ((u >> 16) & 1u);   // round-to-nearest-even
    return (ushort)(u >> 16);
}

// ---------------- prep: X f32 -> Xb bf16 + Xt bf16 (transposed); tail blocks do W->bf16 -------
__global__ __launch_bounds__(256) void prep_kernel(const float* __restrict__ X,
                                                   ushort* __restrict__ Xb,
                                                   ushort* __restrict__ Xt,
                                                   const float* __restrict__ W,
                                                   ushort* __restrict__ Wb) {
    __shared__ ushort T[32 * 33];
    int t   = threadIdx.x;
    int bid = blockIdx.x;              // 8192 X-blocks + 128 W-blocks
    if (bid >= 8192) {
        int gt = (bid - 8192) * 256 + t;
        size_t base = (size_t)gt * 8;
        float4 a = *(const float4*)(W + base);
        float4 c = *(const float4*)(W + base + 4);
        ushort4 lo, hi;
        lo.x = f2bf(a.x); lo.y = f2bf(a.y); lo.z = f2bf(a.z); lo.w = f2bf(a.w);
        hi.x = f2bf(c.x); hi.y = f2bf(c.y); hi.z = f2bf(c.z); hi.w = f2bf(c.w);
        *(ushort4*)(Wb + base)     = lo;
        *(ushort4*)(Wb + base + 4) = hi;
        return;
    }
    int b   = bid >> 10;
    int st  = (bid >> 4) & 63;
    int ht  = bid & 15;
    int s0 = st * 32, h0 = ht * 32;

    int r  = t >> 3;
    int c4 = (t & 7) * 4;
    size_t src = ((size_t)(b * SEQ + s0 + r)) * DIM + h0 + c4;
    float4 v = *(const float4*)(X + src);
    ushort u0 = f2bf(v.x), u1 = f2bf(v.y), u2 = f2bf(v.z), u3 = f2bf(v.w);
    ushort4 uv; uv.x = u0; uv.y = u1; uv.z = u2; uv.w = u3;
    *(ushort4*)(Xb + src) = uv;
    T[(c4 + 0) * 33 + r] = u0;
    T[(c4 + 1) * 33 + r] = u1;
    T[(c4 + 2) * 33 + r] = u2;
    T[(c4 + 3) * 33 + r] = u3;
    __syncthreads();
    int hh = t >> 3;
    int sc = (t & 7) * 4;
    ushort4 w;
    w.x = T[hh * 33 + sc + 0];
    w.y = T[hh * 33 + sc + 1];
    w.z = T[hh * 33 + sc + 2];
    w.w = T[hh * 33 + sc + 3];
    *(ushort4*)(Xt + ((size_t)(b * DIM + h0 + hh)) * SEQ + s0 + sc) = w;
}

// ---------------- qgemm: Qb = bf16(Xb @ Wb^T + bias), depth-2 pipeline (R7) ----------------
__global__ __launch_bounds__(256, 3) void qgemm_kernel(const ushort* __restrict__ Xb,
                                                       const ushort* __restrict__ Wb,
                                                       const float* __restrict__ bias,
                                                       ushort* __restrict__ Qb) {
    __shared__ ushort At[2][128 * 40];
    __shared__ ushort Bt[2][128 * 40];
    int t   = threadIdx.x;
    int bid = blockIdx.x;              // 128 mtiles * 4 ntiles
    int mt = bid >> 2, nt = bid & 3;
    int m0 = mt << 7, n0 = nt << 7;
    int w  = t >> 6, l = t & 63, ln = l & 15, lg = l >> 4;
    int wr = w >> 1, wc = w & 1;

    f32x4 acc[4][4] = {};
    int srow = t >> 2;
    int sc8  = (t & 3) * 8;

    const ushort* Arow = Xb + (size_t)m0 * 512;
    const ushort* Brow = Wb + (size_t)n0 * 512;

#define QG_LOAD(KS, A0, A1, B0, B1)                                                \
    A0 = *(const uint4*)(Arow + (size_t)srow * 512 + (KS) * 32 + sc8);             \
    A1 = *(const uint4*)(Arow + (size_t)(64 + srow) * 512 + (KS) * 32 + sc8);      \
    B0 = *(const uint4*)(Brow + (size_t)srow * 512 + (KS) * 32 + sc8);             \
    B1 = *(const uint4*)(Brow + (size_t)(64 + srow) * 512 + (KS) * 32 + sc8);

#define QG_STORE(CUR, A0, A1, B0, B1)                     \
    {                                                     \
        *(uint4*)&At[CUR][srow * 40 + sc8]        = A0;   \
        *(uint4*)&At[CUR][(64 + srow) * 40 + sc8] = A1;   \
        *(uint4*)&Bt[CUR][srow * 40 + sc8]        = B0;   \
        *(uint4*)&Bt[CUR][(64 + srow) * 40 + sc8] = B1;   \
    }

#define QG_COMPUTE(CUR)                                                                    \
    {                                                                                      \
        bf16x8 af[4], bfr[4];                                                              \
        _Pragma("unroll") for (int r = 0; r < 4; ++r)                                      \
            af[r] = *(const bf16x8*)&At[CUR][(wr * 64 + r * 16 + ln) * 40 + lg * 8];       \
        _Pragma("unroll") for (int cc = 0; cc < 4; ++cc)                                   \
            bfr[cc] = *(const bf16x8*)&Bt[CUR][(wc * 64 + cc * 16 + ln) * 40 + lg * 8];    \
        _Pragma("unroll") for (int r = 0; r < 4; ++r)                                      \
            _Pragma("unroll") for (int cc = 0; cc < 4; ++cc)                               \
                acc[r][cc] = __builtin_amdgcn_mfma_f32_16x16x32_bf16(af[r], bfr[cc],       \
                                                                     acc[r][cc], 0, 0, 0); \
    }

    uint4 pA0, pA1, pB0, pB1, qA0, qA1, qB0, qB1;
    QG_LOAD(0, pA0, pA1, pB0, pB1)
    QG_LOAD(1, qA0, qA1, qB0, qB1)
    QG_STORE(0, pA0, pA1, pB0, pB1)
    __syncthreads();
    for (int ks = 0; ks < 14; ks += 2) {
        QG_LOAD(ks + 2, pA0, pA1, pB0, pB1)
        QG_COMPUTE(0)
        QG_STORE(1, qA0, qA1, qB0, qB1)
        __syncthreads();
        QG_LOAD(ks + 3, qA0, qA1, qB0, qB1)
        QG_COMPUTE(1)
        QG_STORE(0, pA0, pA1, pB0, pB1)
        __syncthreads();
    }
    QG_COMPUTE(0)
    QG_STORE(1, qA0, qA1, qB0, qB1)
    __syncthreads();
    QG_COMPUTE(1)

    float bv[4];
#pragma unroll
    for (int c = 0; c < 4; ++c) bv[c] = bias[n0 + wc * 64 + c * 16 + ln];
#pragma unroll
    for (int r = 0; r < 4; ++r)
#pragma unroll
        for (int c = 0; c < 4; ++c)
#pragma unroll
            for (int q = 0; q < 4; ++q) {
                int row = m0 + wr * 64 + r * 16 + lg * 4 + q;
                int col = n0 + wc * 64 + c * 16 + ln;
                Qb[(size_t)row * 512 + col] = f2bf(acc[r][c][q] + bv[c]);
            }
}

// ---------------- sgemm: P = exp(mask(Q X^T)) -> packed tiles (no den), LDS-bounce store ------
__global__ __launch_bounds__(256, 3) void sgemm_kernel(const ushort* __restrict__ Qb,
                                                       const ushort* __restrict__ Xb,
                                                       ushort* __restrict__ Pb,
                                                       int g0, int G) {
    __shared__ ushort SMEM[20480];     // 40KB: K-loop = At[2]|Bt[2] (pitch 40); epilogue = P tile
#define SG_AT(C) (SMEM + (C) * 5120)
#define SG_BT(C) (SMEM + 10240 + (C) * 5120)
    int t  = threadIdx.x;
    int bL = blockIdx.x;
    int b  = g0 + bL;
    int c  = blockIdx.y;               // 0..135 (uniform work)
    int it = 0, base = 0;
    for (;;) { if (c < base + it + 1) break; base += it + 1; ++it; }
    int jt = c - base;

    int m0 = it << 7, n0 = jt << 7;
    int w  = t >> 6, l = t & 63, ln = l & 15, lg = l >> 4;
    int wr = w >> 1, wc = w & 1;

    const ushort* Arow = Qb + (size_t)(b * SEQ + m0) * 512;
    const ushort* Brow = Xb + (size_t)(b * SEQ + n0) * 512;

    f32x4 acc[4][4] = {};
    int srow = t >> 2;
    int sc8  = (t & 3) * 8;

#define SG_LOAD(KS, A0, A1, B0, B1)                                                \
    A0 = *(const uint4*)(Arow + (size_t)srow * 512 + (KS) * 32 + sc8);             \
    A1 = *(const uint4*)(Arow + (size_t)(64 + srow) * 512 + (KS) * 32 + sc8);      \
    B0 = *(const uint4*)(Brow + (size_t)srow * 512 + (KS) * 32 + sc8);             \
    B1 = *(const uint4*)(Brow + (size_t)(64 + srow) * 512 + (KS) * 32 + sc8);

#define SG_STORE(CUR, A0, A1, B0, B1)                       \
    {                                                       \
        *(uint4*)&SG_AT(CUR)[srow * 40 + sc8]        = A0;  \
        *(uint4*)&SG_AT(CUR)[(64 + srow) * 40 + sc8] = A1;  \
        *(uint4*)&SG_BT(CUR)[srow * 40 + sc8]        = B0;  \
        *(uint4*)&SG_BT(CUR)[(64 + srow) * 40 + sc8] = B1;  \
    }

#define SG_COMPUTE(CUR)                                                                    \
    {                                                                                      \
        bf16x8 af[4], bfr[4];                                                              \
        _Pragma("unroll") for (int r = 0; r < 4; ++r)                                      \
            af[r] = *(const bf16x8*)&SG_AT(CUR)[(wr * 64 + r * 16 + ln) * 40 + lg * 8];    \
        _Pragma("unroll") for (int cc = 0; cc < 4; ++cc)                                   \
            bfr[cc] = *(const bf16x8*)&SG_BT(CUR)[(wc * 64 + cc * 16 + ln) * 40 + lg * 8]; \
        _Pragma("unroll") for (int r = 0; r < 4; ++r)                                      \
            _Pragma("unroll") for (int cc = 0; cc < 4; ++cc)                               \
                acc[r][cc] = __builtin_amdgcn_mfma_f32_16x16x32_bf16(af[r], bfr[cc],       \
                                                                     acc[r][cc], 0, 0, 0); \
    }

    uint4 pA0, pA1, pB0, pB1, qA0, qA1, qB0, qB1;
    SG_LOAD(0, pA0, pA1, pB0, pB1)
    SG_LOAD(1, qA0, qA1, qB0, qB1)
    SG_STORE(0, pA0, pA1, pB0, pB1)
    __syncthreads();
    for (int ks = 0; ks < 14; ks += 2) {
        SG_LOAD(ks + 2, pA0, pA1, pB0, pB1)
        SG_COMPUTE(0)
        SG_STORE(1, qA0, qA1, qB0, qB1)
        __syncthreads();
        SG_LOAD(ks + 3, qA0, qA1, qB0, qB1)
        SG_COMPUTE(1)
        SG_STORE(0, pA0, pA1, pB0, pB1)
        __syncthreads();
    }
    SG_COMPUTE(0)
    SG_STORE(1, qA0, qA1, qB0, qB1)
    __syncthreads();
    SG_COMPUTE(1)
    __syncthreads();                   // LDS free -> reuse as P-tile bounce

    // mask + exp -> LDS P tile [128][128] bf16
#pragma unroll
    for (int r = 0; r < 4; ++r)
#pragma unroll
        for (int q = 0; q < 4; ++q) {
            int prow = wr * 64 + r * 16 + lg * 4 + q;      // local i
            int grow = m0 + prow;                          // in-batch i
#pragma unroll
            for (int cc = 0; cc < 4; ++cc) {
                int pcol = wc * 64 + cc * 16 + ln;
                int col  = n0 + pcol;                      // in-batch j
                float ex = (col < grow) ? __expf(acc[r][cc][q]) : 0.f;
                SMEM[prow * 128 + pcol] = f2bf(ex);
            }
        }
    __syncthreads();

    // coalesced copy-out: 8 x 16B per thread, conflict-free interleave
    ushort* ptile = Pb + ((size_t)c * G + bL) * 16384;
#pragma unroll
    for (int k2 = 0; k2 < 8; ++k2)
        *(uint4*)(ptile + k2 * 2048 + t * 8) = *(const uint4*)(SMEM + k2 * 2048 + t * 8);
}

// ---------------- pvgemm: out = (P @ X)/(den+1e-10), den computed inline, paired tiles --------
__global__ __launch_bounds__(256, 4) void pvgemm_kernel(const ushort* __restrict__ Pb,
                                                        const ushort* __restrict__ Xt,
                                                        float* __restrict__ out,
                                                        int g0, int G) {
    __shared__ ushort Ap[2][128 * 40];
    __shared__ ushort Bp[2][64 * 40];
    __shared__ float  dden[128];
    int t  = threadIdx.x;
    int bL = blockIdx.x;
    int b  = g0 + bL;
    int y  = blockIdx.y;
    int p  = y >> 3;                   // 0..7
    int ht = y & 7;                    // 0..7
    int n0 = ht << 6;

    int w = t >> 6, l = t & 63, ln = l & 15, lg = l >> 4;
    int wr = w >> 1, wc = w & 1;       // wave tile: rows wr*64.., cols wc*32..
    int srow = t >> 2;                 // 0..63
    int sc8  = (t & 3) * 8;

    const ushort* BrowX = Xt + ((size_t)b * DIM + n0) * SEQ;

#define PV_LOAD(KK, A0, A1, B0)                                                    \
    {                                                                              \
        const ushort* ptile = Pb + ((size_t)(Tit + ((KK) >> 2)) * G + bL) * 16384  \
                              + ((KK) & 3) * 32;                                   \
        A0 = *(const uint4*)(ptile + srow * 128 + sc8);                            \
        A1 = *(const uint4*)(ptile + (64 + srow) * 128 + sc8);                     \
        B0 = *(const uint4*)(BrowX + (size_t)srow * SEQ + (KK) * 32 + sc8);        \
    }
#define PV_ST(CUR, A0, A1, B0)                              \
    {                                                       \
        *(uint4*)&Ap[CUR][srow * 40 + sc8]        = A0;     \
        *(uint4*)&Ap[CUR][(64 + srow) * 40 + sc8] = A1;     \
        *(uint4*)&Bp[CUR][srow * 40 + sc8]        = B0;     \
    }
// compute + (wc==0 waves) accumulate row-sums of A fragments for den
#define PV_COMPUTE(CUR)                                                                   \
    {                                                                                     \
        bf16x8 af[4], bfr[2];                                                             \
        _Pragma("unroll") for (int r = 0; r < 4; ++r)                                     \
            af[r] = *(const bf16x8*)&Ap[CUR][(wr * 64 + r * 16 + ln) * 40 + lg * 8];      \
        _Pragma("unroll") for (int cc = 0; cc < 2; ++cc)                                  \
            bfr[cc] = *(const bf16x8*)&Bp[CUR][(wc * 32 + cc * 16 + ln) * 40 + lg * 8];   \
        if (wc == 0) {                                                                    \
            _Pragma("unroll") for (int r = 0; r < 4; ++r)                                 \
                _Pragma("unroll") for (int e = 0; e < 8; ++e)                             \
                    dsum[r] += (float)af[r][e];                                           \
        }                                                                                 \
        _Pragma("unroll") for (int r = 0; r < 4; ++r)                                     \
            _Pragma("unroll") for (int cc = 0; cc < 2; ++cc)                              \
                acc[r][cc] = __builtin_amdgcn_mfma_f32_16x16x32_bf16(af[r], bfr[cc],      \
                                                                     acc[r][cc], 0, 0, 0);\
    }

    for (int half = 0; half < 2; ++half) {
        int it  = half ? p : (15 - p);
        int Tit = (it * (it + 1)) >> 1;
        int n   = (it + 1) * 4;
        int m0  = it << 7;
        f32x4 acc[4][2] = {};
        float dsum[4] = {0.f, 0.f, 0.f, 0.f};

        uint4 pA0, pA1, pB0, qA0, qA1, qB0;
        PV_LOAD(0, pA0, pA1, pB0)
        PV_LOAD(1, qA0, qA1, qB0)
        __syncthreads();               // prev half's readers done (no-op for half 0)
        PV_ST(0, pA0, pA1, pB0)
        __syncthreads();
        for (int ks = 0; ks < n - 2; ks += 2) {
            PV_LOAD(ks + 2, pA0, pA1, pB0)
            PV_COMPUTE(0)
            PV_ST(1, qA0, qA1, qB0)
            __syncthreads();
            if (ks + 3 < n) PV_LOAD(ks + 3, qA0, qA1, qB0)
            PV_COMPUTE(1)
            PV_ST(0, pA0, pA1, pB0)
            __syncthreads();
        }
        PV_COMPUTE(0)
        PV_ST(1, qA0, qA1, qB0)
        __syncthreads();
        PV_COMPUTE(1)

        // den: reduce dsum over the 4 k-chunk lanes (lane-xor 16,32), publish via LDS
        if (wc == 0) {
#pragma unroll
            for (int r = 0; r < 4; ++r) {
                float s = dsum[r];
                s += __shfl_xor(s, 16);
                s += __shfl_xor(s, 32);
                if (lg == 0) dden[wr * 64 + r * 16 + ln] = s;
            }
        }
        __syncthreads();

#pragma unroll
        for (int r = 0; r < 4; ++r)
#pragma unroll
            for (int q = 0; q < 4; ++q) {
                int lrow = wr * 64 + r * 16 + lg * 4 + q;
                int row  = m0 + lrow;
                float inv = 1.0f / (dden[lrow] + 1e-10f);
                size_t o = (size_t)(b * SEQ + row) * 512;
#pragma unroll
                for (int cc = 0; cc < 2; ++cc)
                    out[o + n0 + wc * 32 + cc * 16 + ln] = acc[r][cc][q] * inv;
            }
        __syncthreads();               // protect LDS (tiles + dden) before next half
    }
}

extern "C" void kernel_launch(void* const* d_in, const int* in_sizes, int n_in,
                              void* d_out, int out_size, void* d_ws, size_t ws_size,
                              hipStream_t stream) {
    const float* X    = (const float*)d_in[0];
    const float* W    = (const float*)d_in[1];
    const float* bias = (const float*)d_in[2];
    float* out = (float*)d_out;

    // ws layout (bytes): Xb[16.78M] | Xt[16.78M] | Qb[16.78M] | Wb[0.52M] | Pb[G*4.46M]
    ushort* ws = (ushort*)d_ws;
    ushort* Xb = ws;
    ushort* Xt = ws + 8388608;
    ushort* Qb = ws + 16777216;
    ushort* Wb = ws + 25165824;
    ushort* Pb = (ushort*)((char*)d_ws + 50855936);

    size_t avail = (ws_size > 50855936) ? (ws_size - 50855936) : 0;
    int G = 1;
    while (G < 8 && (size_t)(G * 2) * 4456448 <= avail) G *= 2;

    prep_kernel<<<dim3(8320), dim3(256), 0, stream>>>(X, Xb, Xt, W, Wb);
    qgemm_kernel<<<dim3(512), dim3(256), 0, stream>>>(Xb, Wb, bias, Qb);
    for (int g0 = 0; g0 < BATCH; g0 += G) {
        sgemm_kernel<<<dim3(G, 136), dim3(256), 0, stream>>>(Qb, Xb, Pb, g0, G);
        pvgemm_kernel<<<dim3(G, 64), dim3(256), 0, stream>>>(Pb, Xt, out, g0, G);
    }
}